// Round 9
// baseline (457.615 us; speedup 1.0000x reference)
//
#include <hip/hip_runtime.h>
#include <math.h>

namespace {
constexpr int Vv  = 50257;
constexpr int Dc  = 128;
constexpr int Kc  = 3;
constexpr int NBc = 8;
constexpr int Jc  = 24;      // K*NB
constexpr int Tc  = 64;
constexpr int CHV = 1024;                      // vocab elems per partials chunk
constexpr int NCH = (Vv + CHV - 1) / CHV;      // 50
constexpr int NVC = 512;                       // vocab elems per norm chunk (LDS-staged)
constexpr int NNCH = (Vv + NVC - 1) / NVC;     // 99
constexpr int NTG = 8;                         // t-groups in norm pass
constexpr int TPG = Tc / NTG;                  // 8 t per group
constexpr float INV_SQRT_D = 0.08838834764831845f;
constexpr float DIVW = 2.0f;

// ws layout (float offsets)
constexpr size_t WS_PSI  = 0;        // 24*128
constexpr size_t WS_G    = 4096;     // 24*24 (psi gram)
constexpr size_t WS_BB   = 5120;     // 24*24 (raw bubble gram)
constexpr size_t WS_XN   = 6144;     // 64   |x_t|^2
constexpr size_t WS_BX   = 6400;     // 64*24 bub_j . x_t
constexpr size_t WS_WALL = 8192;     // 64*24
constexpr size_t WS_PART = 12288;    // 64*50*9 = 28800
constexpr size_t WS_P2T  = 65536;    // V*24, layout [v][j]: row = 96B, 16B-aligned

// out layout (float offsets), reference return order
constexpr size_t OFF_TOK = 0;
constexpr size_t OFF_RHO = (size_t)Tc * Vv;
constexpr size_t OFF_S   = OFF_RHO + (size_t)Tc * Dc * Dc;
constexpr size_t OFF_H   = OFF_S + Tc;
constexpr size_t OFF_F   = OFF_H + Tc;
constexpr size_t OFF_PF  = OFF_F + Tc;
}

__device__ __forceinline__ float wsum64(float v) {
#pragma unroll
  for (int m = 1; m < 64; m <<= 1) v += __shfl_xor(v, m);
  return v;
}

// online-softmax merge helpers
__device__ __forceinline__ void comb(float& m1, float& s1, float m2, float s2) {
  float M = fmaxf(m1, m2);
  float e1 = (s1 > 0.f) ? expf(m1 - M) : 0.f;
  float e2 = (s2 > 0.f) ? expf(m2 - M) : 0.f;
  s1 = s1 * e1 + s2 * e2;
  m1 = M;
}
__device__ __forceinline__ void comb_sl(float& m1, float& s1, float& sl1,
                                        float m2, float s2, float sl2) {
  float M = fmaxf(m1, m2);
  float e1 = (s1 > 0.f) ? expf(m1 - M) : 0.f;
  float e2 = (s2 > 0.f) ? expf(m2 - M) : 0.f;
  s1 = s1 * e1 + s2 * e2;
  sl1 = sl1 * e1 + sl2 * e2;
  m1 = M;
}

// shared logit recompute from row-major P2T (used by k_main partials);
// accumulation order is j-ascending within each stream — the norm pass
// replicates the exact same order from its transposed LDS copy.
__device__ __forceinline__ void logits_from_row(const float* __restrict__ p2,
                                                const float* __restrict__ wsh,
                                                int v, float& l0, float& l1, float& l2) {
  const float4* row = (const float4*)(p2 + (size_t)v * Jc);
  float4 q0 = row[0], q1 = row[1], q2 = row[2], q3 = row[3], q4 = row[4], q5 = row[5];
  l0 = 0.f; l1 = 0.f; l2 = 0.f;
  l0 += wsh[0]  * q0.x; l0 += wsh[1]  * q0.y; l0 += wsh[2]  * q0.z; l0 += wsh[3]  * q0.w;
  l0 += wsh[4]  * q1.x; l0 += wsh[5]  * q1.y; l0 += wsh[6]  * q1.z; l0 += wsh[7]  * q1.w;
  l1 += wsh[8]  * q2.x; l1 += wsh[9]  * q2.y; l1 += wsh[10] * q2.z; l1 += wsh[11] * q2.w;
  l1 += wsh[12] * q3.x; l1 += wsh[13] * q3.y; l1 += wsh[14] * q3.z; l1 += wsh[15] * q3.w;
  l2 += wsh[16] * q4.x; l2 += wsh[17] * q4.y; l2 += wsh[18] * q4.z; l2 += wsh[19] * q4.w;
  l2 += wsh[20] * q5.x; l2 += wsh[21] * q5.y; l2 += wsh[22] * q5.z; l2 += wsh[23] * q5.w;
}

// ---------- fused setup: [0] prep | [1..Tc] tok | [Tc+1..] proj ----------
// proj blocks recompute psi locally from bub (identical op sequence to the
// prep block) so there is no intra-launch dependency.
__global__ void k_setup(const int* __restrict__ tok, const float* __restrict__ E,
                        const float* __restrict__ bub, float* __restrict__ ws) {
  __shared__ __align__(16) float braw[Jc * Dc];
  __shared__ __align__(16) float psi[Jc * Dc];
  __shared__ float nrm[Jc];
  int bid = blockIdx.x, tid = threadIdx.x;

  if (bid == 0) {
    // ----- prep: psi + psi-Gram G + raw bubble Gram BB -----
    for (int i = tid; i < Jc * Dc; i += 256) braw[i] = bub[i];
    __syncthreads();
    if (tid < Jc) {
      float s = 0.f;
      for (int d = 0; d < Dc; ++d) { float b = braw[tid * Dc + d]; s += b * b; }
      nrm[tid] = sqrtf(s) + 1e-10f;
    }
    __syncthreads();
    for (int i = tid; i < Jc * Dc; i += 256) {
      float v = braw[i] / nrm[i / Dc];
      psi[i] = v;
      ws[WS_PSI + i] = v;
    }
    __syncthreads();
    for (int i = tid; i < Jc * Jc; i += 256) {
      int r = i / Jc, c = i % Jc;
      float g = 0.f, b = 0.f;
      for (int d = 0; d < Dc; ++d) {
        g += psi[r * Dc + d] * psi[c * Dc + d];
        b += braw[r * Dc + d] * braw[c * Dc + d];
      }
      ws[WS_G + i] = g;
      ws[WS_BB + i] = b;
    }
    return;
  }

  if (bid <= Tc) {
    // ----- tok: BX[t][j] = bub_j . E[tok_t], XN[t] = |x|^2 (one wave) -----
    if (tid >= 64) return;
    int t = bid - 1, lane = tid;
    int tk = tok[t];
    float eA = E[(size_t)tk * Dc + lane];
    float eB = E[(size_t)tk * Dc + 64 + lane];
    float xn = wsum64(eA * eA + eB * eB);
    if (lane == 0) ws[WS_XN + t] = xn;
    float p[Jc];
#pragma unroll
    for (int j = 0; j < Jc; ++j)
      p[j] = bub[j * Dc + lane] * eA + bub[j * Dc + 64 + lane] * eB;
#pragma unroll
    for (int j = 0; j < Jc; ++j) p[j] = wsum64(p[j]);
    if (lane == 0) {
#pragma unroll
      for (int j = 0; j < Jc; ++j) ws[WS_BX + (size_t)t * Jc + j] = p[j];
    }
    return;
  }

  // ----- proj: P2T[v][j] = (E[v].psi_j)^2, psi computed locally -----
  for (int i = tid; i < Jc * Dc; i += 256) braw[i] = bub[i];
  __syncthreads();
  if (tid < Jc) {
    float s = 0.f;
    for (int d = 0; d < Dc; ++d) { float b = braw[tid * Dc + d]; s += b * b; }
    nrm[tid] = sqrtf(s) + 1e-10f;
  }
  __syncthreads();
  for (int i = tid; i < Jc * Dc; i += 256) psi[i] = braw[i] / nrm[i / Dc];
  __syncthreads();
  int v = (bid - Tc - 1) * 256 + tid;
  if (v >= Vv) return;
  float acc[Jc];
#pragma unroll
  for (int j = 0; j < Jc; ++j) acc[j] = 0.f;
  const float4* e4 = (const float4*)(E + (size_t)v * Dc);
  const float4* p4 = (const float4*)psi;
  for (int d = 0; d < Dc / 4; ++d) {
    float4 e = e4[d];
#pragma unroll
    for (int j = 0; j < Jc; ++j) {
      float4 p = p4[j * (Dc / 4) + d];
      acc[j] += e.x * p.x + e.y * p.y + e.z * p.z + e.w * p.w;
    }
  }
  float* o = ws + WS_P2T + (size_t)v * Jc;
#pragma unroll
  for (int j = 0; j < Jc; ++j) o[j] = acc[j] * acc[j];
}

// ---------- sequential recurrence, single wave, register-resident ----------
__global__ void k_recur(const int* __restrict__ tok, const float* __restrict__ E,
                        const float* __restrict__ bub, const float* __restrict__ pdb,
                        const float* __restrict__ psn, float* __restrict__ ws) {
  __shared__ float sBX[Tc * Jc];
  __shared__ float sXN[Tc];
  int lane = threadIdx.x;                 // 64 threads = 1 wave
  for (int i = lane; i < Tc * Jc; i += 64) sBX[i] = ws[WS_BX + i];
  if (lane < Tc) sXN[lane] = ws[WS_XN + lane];
  float db = pdb[0];
  float sens = fabsf(psn[0]);
  int tokv = tok[lane];
  float bubA[Jc], bubB[Jc];
#pragma unroll
  for (int j = 0; j < Jc; ++j) {
    bubA[j] = bub[j * Dc + lane];
    bubB[j] = bub[j * Dc + 64 + lane];
  }
  int jme = (lane < Jc) ? lane : (Jc - 1);
  int kme = jme >> 3;
  float BBrow[Jc];
#pragma unroll
  for (int j = 0; j < Jc; ++j) BBrow[j] = ws[WS_BB + (size_t)jme * Jc + j];
  __syncthreads();
  float mmA[Kc] = {0.f, 0.f, 0.f}, mmB[Kc] = {0.f, 0.f, 0.f};
  float BMv[Kc] = {0.f, 0.f, 0.f};
  int tk0 = __shfl(tokv, 0);
  float xA = E[(size_t)tk0 * Dc + lane];
  float xB = E[(size_t)tk0 * Dc + 64 + lane];
  for (int t = 0; t < Tc; ++t) {
    float nxA = 0.f, nxB = 0.f;
    if (t + 1 < Tc) {
      int nk = __shfl(tokv, t + 1);
      nxA = E[(size_t)nk * Dc + lane];
      nxB = E[(size_t)nk * Dc + 64 + lane];
    }
    float dk[Kc], nk2[Kc];
#pragma unroll
    for (int k = 0; k < Kc; ++k) {
      dk[k]  = wsum64(mmA[k] * xA + mmB[k] * xB);
      nk2[k] = wsum64(mmA[k] * mmA[k] + mmB[k] * mmB[k]);
    }
    float xn = sqrtf(sXN[t]) + 1e-10f;
    float dec[Kc], xmA[Kc], xmB[Kc];
#pragma unroll
    for (int k = 0; k < Kc; ++k) {
      float mn = sqrtf(nk2[k]) + 1e-10f;
      float cosv = dk[k] / (xn * mn);
      float nov = (mn > 1e-8f) ? (1.f - cosv) : 1.f;
      dec[k] = 1.f / (1.f + expf(-(db - sens * nov)));
      xmA[k] = xA + dec[k] * mmA[k];
      xmB[k] = xB + dec[k] * mmB[k];
    }
    float bxj = sBX[t * Jc + jme];
    float decS = (kme == 0) ? dec[0] : ((kme == 1) ? dec[1] : dec[2]);
    float sc = (bxj + decS * BMv[kme]) * (DIVW * INV_SQRT_D);
    float mx = sc;
    mx = fmaxf(mx, __shfl_xor(mx, 1));
    mx = fmaxf(mx, __shfl_xor(mx, 2));
    mx = fmaxf(mx, __shfl_xor(mx, 4));
    float e = expf(sc - mx);
    float ss = e;
    ss += __shfl_xor(ss, 1);
    ss += __shfl_xor(ss, 2);
    ss += __shfl_xor(ss, 4);
    float w = e / ss;
    if (lane < Jc) ws[WS_WALL + (size_t)t * Jc + lane] = w;
    float wj[Jc];
#pragma unroll
    for (int j = 0; j < Jc; ++j) wj[j] = __shfl(w, j);
#pragma unroll
    for (int k = 0; k < Kc; ++k) {
      float accA = 0.f, accB = 0.f;
#pragma unroll
      for (int n = 0; n < NBc; ++n) {
        float om = 1.f - wj[k * NBc + n];
        accA += om * bubA[k * NBc + n];
        accB += om * bubB[k * NBc + n];
      }
      float od8 = (1.f - dec[k]) * 0.125f;
      mmA[k] = dec[k] * mmA[k] + od8 * (xmA[k] + accA);
      mmB[k] = dec[k] * mmB[k] + od8 * (xmB[k] + accB);
    }
#pragma unroll
    for (int k = 0; k < Kc; ++k) {
      float bxm = bxj + dec[k] * BMv[k];
      float s2 = 0.f;
#pragma unroll
      for (int n = 0; n < NBc; ++n) s2 += (1.f - wj[k * NBc + n]) * BBrow[k * NBc + n];
      BMv[k] = dec[k] * BMv[k] + (1.f - dec[k]) * 0.125f * (bxm + s2);
    }
    xA = nxA; xB = nxB;
  }
}

// ---------- fused main: [0,64) eig | [64,128) rho | [128,..) softmax partials ----------
__global__ void k_main(float* __restrict__ ws, float* __restrict__ out) {
  __shared__ float sh[Jc * Dc];        // rho: psis (12KB); eig: A (600 floats used)
  __shared__ float wsh[Jc];
  __shared__ float rm[4][4], rs[4][4], rsl2[4];
  int bid = blockIdx.x, tid = threadIdx.x;

  if (bid < Tc) {
    // ----- eig branch: one wave per t, R0-proven LDS Jacobi -----
    if (tid >= 64) return;
    int t = bid, lane = tid;
    float* A = sh;                     // stride 25: bank-decorrelated
    for (int i = lane; i < Jc * Jc; i += 64) {
      int r = i / Jc, c = i % Jc;
      A[r * 25 + c] = ws[WS_G + i] *
                      sqrtf(ws[WS_WALL + (size_t)t * Jc + r] * ws[WS_WALL + (size_t)t * Jc + c]) *
                      (1.f / 3.f);
    }
    __builtin_amdgcn_wave_barrier();
    for (int sweep = 0; sweep < 7; ++sweep) {
      for (int rr = 0; rr < 23; ++rr) {
        float cv = 1.f, sv = 0.f;
        if (lane < Jc) {
          int j = lane;
          int m = (j == 23) ? rr : ((j == rr) ? 23 : (2 * rr + 23 - j) % 23);
          int lo = min(j, m), hi = max(j, m);
          float ajj = A[j * 25 + j];
          float alh = A[lo * 25 + hi];
          float amm = __shfl(ajj, m);
          float app = (j == lo) ? ajj : amm;
          float aqq = (j == lo) ? amm : ajj;
          if (fabsf(alh) > 1e-20f) {
            float th = (aqq - app) / (2.f * alh);
            float tt = 1.f / (fabsf(th) + sqrtf(1.f + th * th));
            if (th < 0.f) tt = -tt;
            cv = 1.f / sqrtf(1.f + tt * tt);
            sv = tt * cv;
          }
        }
        __builtin_amdgcn_wave_barrier();
#pragma unroll
        for (int it = 0; it < 3; ++it) {
          int b = lane + 64 * it;
          int bb = (b < 144) ? b : 143;
          int pi = bb / 12, pj = bb % 12;
          int p0, q0, p1, q1;
          if (pi == 0) { p0 = rr; q0 = 23; }
          else { int a = (rr + pi) % 23, b2 = (rr + 23 - pi) % 23; p0 = min(a, b2); q0 = max(a, b2); }
          if (pj == 0) { p1 = rr; q1 = 23; }
          else { int a = (rr + pj) % 23, b2 = (rr + 23 - pj) % 23; p1 = min(a, b2); q1 = max(a, b2); }
          float ci = __shfl(cv, p0), si = __shfl(sv, p0);
          float cj = __shfl(cv, p1), sj = __shfl(sv, p1);
          if (b < 144) {
            float m00 = A[p0 * 25 + p1], m01 = A[p0 * 25 + q1];
            float m10 = A[q0 * 25 + p1], m11 = A[q0 * 25 + q1];
            float r00 = ci * m00 - si * m10, r01 = ci * m01 - si * m11;
            float r10 = si * m00 + ci * m10, r11 = si * m01 + ci * m11;
            float o00 = cj * r00 - sj * r01, o01 = sj * r00 + cj * r01;
            float o10 = cj * r10 - sj * r11, o11 = sj * r10 + cj * r11;
            A[p0 * 25 + p1] = o00; A[p0 * 25 + q1] = o01;
            A[q0 * 25 + p1] = o10; A[q0 * 25 + q1] = o11;
          }
        }
        __builtin_amdgcn_wave_barrier();
      }
    }
    float lam = 0.f;
    if (lane < Jc) lam = fmaxf(A[lane * 25 + lane], 1e-12f);
    float tot = lam;
#pragma unroll
    for (int off = 32; off; off >>= 1) tot += __shfl_down(tot, off);
    tot = __shfl(tot, 0);
    tot += (float)(Dc - Jc) * 1e-12f;
    float term = 0.f;
    if (lane < Jc) { float p = lam / tot; term = p * logf(p); }
#pragma unroll
    for (int off = 32; off; off >>= 1) term += __shfl_down(term, off);
    if (lane == 0) {
      float pe = 1e-12f / tot;
      out[OFF_S + t] = -(term + (float)(Dc - Jc) * pe * logf(pe));
    }
    return;
  }

  if (bid < 2 * Tc) {
    // ----- rho branch: rho[t] = sum_j (w_j/3) psi_j psi_j^T -----
    int t = bid - Tc;
    float* psis = sh;
    for (int i = tid; i < Jc * Dc; i += 256) psis[i] = ws[WS_PSI + i];
    if (tid < Jc) wsh[tid] = ws[WS_WALL + (size_t)t * Jc + tid] * (1.f / 3.f);
    __syncthreads();
    int d = tid >> 1, eh = (tid & 1) * 64;
    float4 acc[16];
#pragma unroll
    for (int i = 0; i < 16; ++i) acc[i] = make_float4(0.f, 0.f, 0.f, 0.f);
    for (int j = 0; j < Jc; ++j) {
      float a = wsh[j] * psis[j * Dc + d];
      const float4* pr = (const float4*)&psis[j * Dc + eh];
#pragma unroll
      for (int i = 0; i < 16; ++i) {
        float4 p = pr[i];
        acc[i].x += a * p.x; acc[i].y += a * p.y; acc[i].z += a * p.z; acc[i].w += a * p.w;
      }
    }
    float* o = out + OFF_RHO + (size_t)t * Dc * Dc + (size_t)d * Dc + eh;
#pragma unroll
    for (int i = 0; i < 16; ++i) ((float4*)o)[i] = acc[i];
    return;
  }

  // ----- partials branch: recompute logits from P2T[v][j], online softmax -----
  int lin = bid - 2 * Tc;
  int t = lin / NCH, ch = lin % NCH;
  if (tid < Jc) wsh[tid] = ws[WS_WALL + (size_t)t * Jc + tid];
  __syncthreads();
  float m[4] = {-INFINITY, -INFINITY, -INFINITY, -INFINITY};
  float s[4] = {0.f, 0.f, 0.f, 0.f};
  float sl = 0.f;
  const float* p2 = ws + WS_P2T;
  for (int r = 0; r < 4; ++r) {
    int v = ch * CHV + r * 256 + tid;
    if (v >= Vv) break;
    float l0, l1, l2;
    logits_from_row(p2, wsh, v, l0, l1, l2);
    float l[4] = { l0, l1, l2, (l0 + l1 + l2) * (1.f / 3.f) };
#pragma unroll
    for (int d = 0; d < 4; ++d) {
      float li = l[d];
      if (li > m[d]) {
        float e = expf(m[d] - li);
        s[d] = s[d] * e + 1.f;
        if (d == 3) sl = sl * e + li;
        m[d] = li;
      } else {
        float e = expf(li - m[d]);
        s[d] += e;
        if (d == 3) sl += e * li;
      }
    }
  }
#pragma unroll
  for (int off = 32; off; off >>= 1) {
#pragma unroll
    for (int d = 0; d < 3; ++d) {
      float om = __shfl_down(m[d], off);
      float os = __shfl_down(s[d], off);
      comb(m[d], s[d], om, os);
    }
    float om = __shfl_down(m[3], off);
    float os = __shfl_down(s[3], off);
    float osl = __shfl_down(sl, off);
    comb_sl(m[3], s[3], sl, om, os, osl);
  }
  int wv = tid >> 6, ln = tid & 63;
  if (ln == 0) {
#pragma unroll
    for (int d = 0; d < 4; ++d) { rm[wv][d] = m[d]; rs[wv][d] = s[d]; }
    rsl2[wv] = sl;
  }
  __syncthreads();
  if (tid == 0) {
    float* part = ws + WS_PART + ((size_t)t * NCH + ch) * 9;
    for (int d = 0; d < 3; ++d) {
      float M = rm[0][d], S = rs[0][d];
      for (int w2 = 1; w2 < 4; ++w2) comb(M, S, rm[w2][d], rs[w2][d]);
      part[d] = M; part[4 + d] = S;
    }
    float M = rm[0][3], S = rs[0][3], SL = rsl2[0];
    for (int w2 = 1; w2 < 4; ++w2) comb_sl(M, S, SL, rm[w2][3], rs[w2][3], rsl2[w2]);
    part[3] = M; part[7] = S; part[8] = SL;
  }
}

// ---------- norm pass: LDS-staged P2T chunk, inline logZ reduce, all outputs ----------
// Each block: one 512-v chunk transposed into LDS (read once, used for 8 t's).
// logZ recomputed per block in identical ch-order to the old k_reduce.
__global__ void k_norm2(const float* __restrict__ ws, float* __restrict__ out) {
  __shared__ float p2s[Jc][NVC];       // 48 KB, transposed: [j][v_local]
  __shared__ float wshA[TPG][Jc];
  __shared__ float lzsA[TPG][4];
  int chv = blockIdx.x, tg = blockIdx.y, tid = threadIdx.x;
  int v0 = chv * NVC;
  int t0 = tg * TPG;

  // stage chunk (2 rows per thread), transposed store (per-inst conflict-free)
#pragma unroll
  for (int rr = 0; rr < 2; ++rr) {
    int vl = tid * 2 + rr;
    int v = v0 + vl;
    if (v < Vv) {
      const float4* row = (const float4*)(ws + WS_P2T + (size_t)v * Jc);
      float4 q0 = row[0], q1 = row[1], q2 = row[2], q3 = row[3], q4 = row[4], q5 = row[5];
      p2s[0][vl] = q0.x;  p2s[1][vl] = q0.y;  p2s[2][vl] = q0.z;  p2s[3][vl] = q0.w;
      p2s[4][vl] = q1.x;  p2s[5][vl] = q1.y;  p2s[6][vl] = q1.z;  p2s[7][vl] = q1.w;
      p2s[8][vl] = q2.x;  p2s[9][vl] = q2.y;  p2s[10][vl] = q2.z; p2s[11][vl] = q2.w;
      p2s[12][vl] = q3.x; p2s[13][vl] = q3.y; p2s[14][vl] = q3.z; p2s[15][vl] = q3.w;
      p2s[16][vl] = q4.x; p2s[17][vl] = q4.y; p2s[18][vl] = q4.z; p2s[19][vl] = q4.w;
      p2s[20][vl] = q5.x; p2s[21][vl] = q5.y; p2s[22][vl] = q5.z; p2s[23][vl] = q5.w;
    }
  }
  // wall weights for this t-group
  if (tid < TPG * Jc)
    wshA[tid / Jc][tid % Jc] = ws[WS_WALL + (size_t)(t0 + tid / Jc) * Jc + (tid % Jc)];
  // inline logZ reduce: 32 threads handle (tt, d) pairs, ch-order identical to k_reduce
  if (tid >= 192 && tid < 192 + TPG * 4) {
    int p = tid - 192;
    int tt = p >> 2, d = p & 3;
    int t = t0 + tt;
    float M = -INFINITY, S = 0.f, SL = 0.f;
    for (int ch = 0; ch < NCH; ++ch) {
      const float* pp = ws + WS_PART + ((size_t)t * NCH + ch) * 9;
      if (d == 3) comb_sl(M, S, SL, pp[3], pp[7], pp[8]);
      else        comb(M, S, pp[d], pp[4 + d]);
    }
    float lz = M + logf(S);
    lzsA[tt][d] = lz;
    if (d == 3 && chv == 0) {
      float H = lz - SL / S;
      float Srho = out[OFF_S + t];
      out[OFF_H + t] = H;
      out[OFF_F + t] = H - Srho;
    }
  }
  __syncthreads();

  for (int tt = 0; tt < TPG; ++tt) {
    int t = t0 + tt;
    float lz0 = lzsA[tt][0], lz1 = lzsA[tt][1], lz2 = lzsA[tt][2], lz3 = lzsA[tt][3];
#pragma unroll
    for (int rr = 0; rr < 2; ++rr) {
      int vl = tid + rr * 256;
      int v = v0 + vl;
      if (v >= Vv) continue;
      // j-ascending accumulation, identical order to logits_from_row
      float l0 = 0.f, l1 = 0.f, l2 = 0.f;
      l0 += wshA[tt][0]  * p2s[0][vl];  l0 += wshA[tt][1]  * p2s[1][vl];
      l0 += wshA[tt][2]  * p2s[2][vl];  l0 += wshA[tt][3]  * p2s[3][vl];
      l0 += wshA[tt][4]  * p2s[4][vl];  l0 += wshA[tt][5]  * p2s[5][vl];
      l0 += wshA[tt][6]  * p2s[6][vl];  l0 += wshA[tt][7]  * p2s[7][vl];
      l1 += wshA[tt][8]  * p2s[8][vl];  l1 += wshA[tt][9]  * p2s[9][vl];
      l1 += wshA[tt][10] * p2s[10][vl]; l1 += wshA[tt][11] * p2s[11][vl];
      l1 += wshA[tt][12] * p2s[12][vl]; l1 += wshA[tt][13] * p2s[13][vl];
      l1 += wshA[tt][14] * p2s[14][vl]; l1 += wshA[tt][15] * p2s[15][vl];
      l2 += wshA[tt][16] * p2s[16][vl]; l2 += wshA[tt][17] * p2s[17][vl];
      l2 += wshA[tt][18] * p2s[18][vl]; l2 += wshA[tt][19] * p2s[19][vl];
      l2 += wshA[tt][20] * p2s[20][vl]; l2 += wshA[tt][21] * p2s[21][vl];
      l2 += wshA[tt][22] * p2s[22][vl]; l2 += wshA[tt][23] * p2s[23][vl];
      float l3 = (l0 + l1 + l2) * (1.f / 3.f);
      out[OFF_TOK + (size_t)t * Vv + v] = expf(l3 - lz3);
      out[OFF_PF + ((size_t)t * Kc + 0) * Vv + v] = expf(l0 - lz0);
      out[OFF_PF + ((size_t)t * Kc + 1) * Vv + v] = expf(l1 - lz1);
      out[OFF_PF + ((size_t)t * Kc + 2) * Vv + v] = expf(l2 - lz2);
    }
  }
}

extern "C" void kernel_launch(void* const* d_in, const int* in_sizes, int n_in,
                              void* d_out, int out_size, void* d_ws, size_t ws_size,
                              hipStream_t stream) {
  const int*   tokens = (const int*)d_in[0];
  const float* E      = (const float*)d_in[1];
  const float* bub    = (const float*)d_in[2];
  const float* pdb    = (const float*)d_in[3];
  const float* psn    = (const float*)d_in[4];
  float* out = (float*)d_out;
  float* ws  = (float*)d_ws;

  k_setup<<<1 + Tc + (Vv + 255) / 256, 256, 0, stream>>>(tokens, E, bub, ws);
  k_recur<<<1, 64, 0, stream>>>(tokens, E, bub, pdb, psn, ws);
  k_main<<<2 * Tc + Tc * NCH, 256, 0, stream>>>(ws, out);
  k_norm2<<<dim3(NNCH, NTG), 256, 0, stream>>>(ws, out);
}

// Round 10
// 428.937 us; speedup vs baseline: 1.0669x; 1.0669x over previous
//
#include <hip/hip_runtime.h>
#include <math.h>

namespace {
constexpr int Vv  = 50257;
constexpr int Dc  = 128;
constexpr int Kc  = 3;
constexpr int NBc = 8;
constexpr int Jc  = 24;      // K*NB
constexpr int Tc  = 64;
constexpr int CHV = 1024;                      // vocab elems per chunk
constexpr int NCH = (Vv + CHV - 1) / CHV;      // 50
constexpr float INV_SQRT_D = 0.08838834764831845f;
constexpr float DIVW = 2.0f;

// ws layout (float offsets)
constexpr size_t WS_PSI  = 0;        // 24*128
constexpr size_t WS_G    = 4096;     // 24*24 (psi gram)
constexpr size_t WS_BB   = 5120;     // 24*24 (raw bubble gram)
constexpr size_t WS_XN   = 6144;     // 64   |x_t|^2
constexpr size_t WS_BX   = 6400;     // 64*24 bub_j . x_t
constexpr size_t WS_WALL = 8192;     // 64*24
constexpr size_t WS_PART = 12288;    // 64*50*9 = 28800
constexpr size_t WS_P2T  = 65536;    // V*24, layout [v][j]: row = 96B, 16B-aligned

// out layout (float offsets), reference return order
constexpr size_t OFF_TOK = 0;
constexpr size_t OFF_RHO = (size_t)Tc * Vv;
constexpr size_t OFF_S   = OFF_RHO + (size_t)Tc * Dc * Dc;
constexpr size_t OFF_H   = OFF_S + Tc;
constexpr size_t OFF_F   = OFF_H + Tc;
constexpr size_t OFF_PF  = OFF_F + Tc;
}

__device__ __forceinline__ float wsum64(float v) {
#pragma unroll
  for (int m = 1; m < 64; m <<= 1) v += __shfl_xor(v, m);
  return v;
}

// online-softmax merge helpers
__device__ __forceinline__ void comb(float& m1, float& s1, float m2, float s2) {
  float M = fmaxf(m1, m2);
  float e1 = (s1 > 0.f) ? expf(m1 - M) : 0.f;
  float e2 = (s2 > 0.f) ? expf(m2 - M) : 0.f;
  s1 = s1 * e1 + s2 * e2;
  m1 = M;
}
__device__ __forceinline__ void comb_sl(float& m1, float& s1, float& sl1,
                                        float m2, float s2, float sl2) {
  float M = fmaxf(m1, m2);
  float e1 = (s1 > 0.f) ? expf(m1 - M) : 0.f;
  float e2 = (s2 > 0.f) ? expf(m2 - M) : 0.f;
  s1 = s1 * e1 + s2 * e2;
  sl1 = sl1 * e1 + sl2 * e2;
  m1 = M;
}

// shared logit recompute from row-major P2T; identical op order everywhere.
__device__ __forceinline__ void logits_from_row(const float* __restrict__ p2,
                                                const float* __restrict__ wsh,
                                                int v, float& l0, float& l1, float& l2) {
  const float4* row = (const float4*)(p2 + (size_t)v * Jc);
  float4 q0 = row[0], q1 = row[1], q2 = row[2], q3 = row[3], q4 = row[4], q5 = row[5];
  l0 = 0.f; l1 = 0.f; l2 = 0.f;
  l0 += wsh[0]  * q0.x; l0 += wsh[1]  * q0.y; l0 += wsh[2]  * q0.z; l0 += wsh[3]  * q0.w;
  l0 += wsh[4]  * q1.x; l0 += wsh[5]  * q1.y; l0 += wsh[6]  * q1.z; l0 += wsh[7]  * q1.w;
  l1 += wsh[8]  * q2.x; l1 += wsh[9]  * q2.y; l1 += wsh[10] * q2.z; l1 += wsh[11] * q2.w;
  l1 += wsh[12] * q3.x; l1 += wsh[13] * q3.y; l1 += wsh[14] * q3.z; l1 += wsh[15] * q3.w;
  l2 += wsh[16] * q4.x; l2 += wsh[17] * q4.y; l2 += wsh[18] * q4.z; l2 += wsh[19] * q4.w;
  l2 += wsh[20] * q5.x; l2 += wsh[21] * q5.y; l2 += wsh[22] * q5.z; l2 += wsh[23] * q5.w;
}

// ---------- fused setup: [0] prep | [1..Tc] tok | [Tc+1..] proj ----------
__global__ void k_setup(const int* __restrict__ tok, const float* __restrict__ E,
                        const float* __restrict__ bub, float* __restrict__ ws) {
  __shared__ __align__(16) float braw[Jc * Dc];
  __shared__ __align__(16) float psi[Jc * Dc];
  __shared__ float nrm[Jc];
  int bid = blockIdx.x, tid = threadIdx.x;

  if (bid == 0) {
    for (int i = tid; i < Jc * Dc; i += 256) braw[i] = bub[i];
    __syncthreads();
    if (tid < Jc) {
      float s = 0.f;
      for (int d = 0; d < Dc; ++d) { float b = braw[tid * Dc + d]; s += b * b; }
      nrm[tid] = sqrtf(s) + 1e-10f;
    }
    __syncthreads();
    for (int i = tid; i < Jc * Dc; i += 256) {
      float v = braw[i] / nrm[i / Dc];
      psi[i] = v;
      ws[WS_PSI + i] = v;
    }
    __syncthreads();
    for (int i = tid; i < Jc * Jc; i += 256) {
      int r = i / Jc, c = i % Jc;
      float g = 0.f, b = 0.f;
      for (int d = 0; d < Dc; ++d) {
        g += psi[r * Dc + d] * psi[c * Dc + d];
        b += braw[r * Dc + d] * braw[c * Dc + d];
      }
      ws[WS_G + i] = g;
      ws[WS_BB + i] = b;
    }
    return;
  }

  if (bid <= Tc) {
    if (tid >= 64) return;
    int t = bid - 1, lane = tid;
    int tk = tok[t];
    float eA = E[(size_t)tk * Dc + lane];
    float eB = E[(size_t)tk * Dc + 64 + lane];
    float xn = wsum64(eA * eA + eB * eB);
    if (lane == 0) ws[WS_XN + t] = xn;
    float p[Jc];
#pragma unroll
    for (int j = 0; j < Jc; ++j)
      p[j] = bub[j * Dc + lane] * eA + bub[j * Dc + 64 + lane] * eB;
#pragma unroll
    for (int j = 0; j < Jc; ++j) p[j] = wsum64(p[j]);
    if (lane == 0) {
#pragma unroll
      for (int j = 0; j < Jc; ++j) ws[WS_BX + (size_t)t * Jc + j] = p[j];
    }
    return;
  }

  // proj: P2T[v][j] = (E[v].psi_j)^2, psi computed locally (no dependency)
  for (int i = tid; i < Jc * Dc; i += 256) braw[i] = bub[i];
  __syncthreads();
  if (tid < Jc) {
    float s = 0.f;
    for (int d = 0; d < Dc; ++d) { float b = braw[tid * Dc + d]; s += b * b; }
    nrm[tid] = sqrtf(s) + 1e-10f;
  }
  __syncthreads();
  for (int i = tid; i < Jc * Dc; i += 256) psi[i] = braw[i] / nrm[i / Dc];
  __syncthreads();
  int v = (bid - Tc - 1) * 256 + tid;
  if (v >= Vv) return;
  float acc[Jc];
#pragma unroll
  for (int j = 0; j < Jc; ++j) acc[j] = 0.f;
  const float4* e4 = (const float4*)(E + (size_t)v * Dc);
  const float4* p4 = (const float4*)psi;
  for (int d = 0; d < Dc / 4; ++d) {
    float4 e = e4[d];
#pragma unroll
    for (int j = 0; j < Jc; ++j) {
      float4 p = p4[j * (Dc / 4) + d];
      acc[j] += e.x * p.x + e.y * p.y + e.z * p.z + e.w * p.w;
    }
  }
  float* o = ws + WS_P2T + (size_t)v * Jc;
#pragma unroll
  for (int j = 0; j < Jc; ++j) o[j] = acc[j] * acc[j];
}

// ---------- sequential recurrence, single wave, register-resident ----------
__global__ void k_recur(const int* __restrict__ tok, const float* __restrict__ E,
                        const float* __restrict__ bub, const float* __restrict__ pdb,
                        const float* __restrict__ psn, float* __restrict__ ws) {
  __shared__ float sBX[Tc * Jc];
  __shared__ float sXN[Tc];
  int lane = threadIdx.x;                 // 64 threads = 1 wave
  for (int i = lane; i < Tc * Jc; i += 64) sBX[i] = ws[WS_BX + i];
  if (lane < Tc) sXN[lane] = ws[WS_XN + lane];
  float db = pdb[0];
  float sens = fabsf(psn[0]);
  int tokv = tok[lane];
  float bubA[Jc], bubB[Jc];
#pragma unroll
  for (int j = 0; j < Jc; ++j) {
    bubA[j] = bub[j * Dc + lane];
    bubB[j] = bub[j * Dc + 64 + lane];
  }
  int jme = (lane < Jc) ? lane : (Jc - 1);
  int kme = jme >> 3;
  float BBrow[Jc];
#pragma unroll
  for (int j = 0; j < Jc; ++j) BBrow[j] = ws[WS_BB + (size_t)jme * Jc + j];
  __syncthreads();
  float mmA[Kc] = {0.f, 0.f, 0.f}, mmB[Kc] = {0.f, 0.f, 0.f};
  float BMv[Kc] = {0.f, 0.f, 0.f};
  int tk0 = __shfl(tokv, 0);
  float xA = E[(size_t)tk0 * Dc + lane];
  float xB = E[(size_t)tk0 * Dc + 64 + lane];
  for (int t = 0; t < Tc; ++t) {
    float nxA = 0.f, nxB = 0.f;
    if (t + 1 < Tc) {
      int nk = __shfl(tokv, t + 1);
      nxA = E[(size_t)nk * Dc + lane];
      nxB = E[(size_t)nk * Dc + 64 + lane];
    }
    float dk[Kc], nk2[Kc];
#pragma unroll
    for (int k = 0; k < Kc; ++k) {
      dk[k]  = wsum64(mmA[k] * xA + mmB[k] * xB);
      nk2[k] = wsum64(mmA[k] * mmA[k] + mmB[k] * mmB[k]);
    }
    float xn = sqrtf(sXN[t]) + 1e-10f;
    float dec[Kc], xmA[Kc], xmB[Kc];
#pragma unroll
    for (int k = 0; k < Kc; ++k) {
      float mn = sqrtf(nk2[k]) + 1e-10f;
      float cosv = dk[k] / (xn * mn);
      float nov = (mn > 1e-8f) ? (1.f - cosv) : 1.f;
      dec[k] = 1.f / (1.f + expf(-(db - sens * nov)));
      xmA[k] = xA + dec[k] * mmA[k];
      xmB[k] = xB + dec[k] * mmB[k];
    }
    float bxj = sBX[t * Jc + jme];
    float decS = (kme == 0) ? dec[0] : ((kme == 1) ? dec[1] : dec[2]);
    float sc = (bxj + decS * BMv[kme]) * (DIVW * INV_SQRT_D);
    float mx = sc;
    mx = fmaxf(mx, __shfl_xor(mx, 1));
    mx = fmaxf(mx, __shfl_xor(mx, 2));
    mx = fmaxf(mx, __shfl_xor(mx, 4));
    float e = expf(sc - mx);
    float ss = e;
    ss += __shfl_xor(ss, 1);
    ss += __shfl_xor(ss, 2);
    ss += __shfl_xor(ss, 4);
    float w = e / ss;
    if (lane < Jc) ws[WS_WALL + (size_t)t * Jc + lane] = w;
    float wj[Jc];
#pragma unroll
    for (int j = 0; j < Jc; ++j) wj[j] = __shfl(w, j);
#pragma unroll
    for (int k = 0; k < Kc; ++k) {
      float accA = 0.f, accB = 0.f;
#pragma unroll
      for (int n = 0; n < NBc; ++n) {
        float om = 1.f - wj[k * NBc + n];
        accA += om * bubA[k * NBc + n];
        accB += om * bubB[k * NBc + n];
      }
      float od8 = (1.f - dec[k]) * 0.125f;
      mmA[k] = dec[k] * mmA[k] + od8 * (xmA[k] + accA);
      mmB[k] = dec[k] * mmB[k] + od8 * (xmB[k] + accB);
    }
#pragma unroll
    for (int k = 0; k < Kc; ++k) {
      float bxm = bxj + dec[k] * BMv[k];
      float s2 = 0.f;
#pragma unroll
      for (int n = 0; n < NBc; ++n) s2 += (1.f - wj[k * NBc + n]) * BBrow[k * NBc + n];
      BMv[k] = dec[k] * BMv[k] + (1.f - dec[k]) * 0.125f * (bxm + s2);
    }
    xA = nxA; xB = nxB;
  }
}

// ---------- k_part: [0,64) rho | [64,..) softmax partials ----------
__global__ void k_part(float* __restrict__ ws, float* __restrict__ out) {
  __shared__ float sh[Jc * Dc];
  __shared__ float wsh[Jc];
  __shared__ float rm[4][4], rs[4][4], rsl2[4];
  int bid = blockIdx.x, tid = threadIdx.x;

  if (bid < Tc) {
    // rho branch
    int t = bid;
    float* psis = sh;
    for (int i = tid; i < Jc * Dc; i += 256) psis[i] = ws[WS_PSI + i];
    if (tid < Jc) wsh[tid] = ws[WS_WALL + (size_t)t * Jc + tid] * (1.f / 3.f);
    __syncthreads();
    int d = tid >> 1, eh = (tid & 1) * 64;
    float4 acc[16];
#pragma unroll
    for (int i = 0; i < 16; ++i) acc[i] = make_float4(0.f, 0.f, 0.f, 0.f);
    for (int j = 0; j < Jc; ++j) {
      float a = wsh[j] * psis[j * Dc + d];
      const float4* pr = (const float4*)&psis[j * Dc + eh];
#pragma unroll
      for (int i = 0; i < 16; ++i) {
        float4 p = pr[i];
        acc[i].x += a * p.x; acc[i].y += a * p.y; acc[i].z += a * p.z; acc[i].w += a * p.w;
      }
    }
    float* o = out + OFF_RHO + (size_t)t * Dc * Dc + (size_t)d * Dc + eh;
#pragma unroll
    for (int i = 0; i < 16; ++i) ((float4*)o)[i] = acc[i];
    return;
  }

  // partials branch
  int lin = bid - Tc;
  int t = lin / NCH, ch = lin % NCH;
  if (tid < Jc) wsh[tid] = ws[WS_WALL + (size_t)t * Jc + tid];
  __syncthreads();
  float m[4] = {-INFINITY, -INFINITY, -INFINITY, -INFINITY};
  float s[4] = {0.f, 0.f, 0.f, 0.f};
  float sl = 0.f;
  const float* p2 = ws + WS_P2T;
  for (int r = 0; r < 4; ++r) {
    int v = ch * CHV + r * 256 + tid;
    if (v >= Vv) break;
    float l0, l1, l2;
    logits_from_row(p2, wsh, v, l0, l1, l2);
    float l[4] = { l0, l1, l2, (l0 + l1 + l2) * (1.f / 3.f) };
#pragma unroll
    for (int d = 0; d < 4; ++d) {
      float li = l[d];
      if (li > m[d]) {
        float e = expf(m[d] - li);
        s[d] = s[d] * e + 1.f;
        if (d == 3) sl = sl * e + li;
        m[d] = li;
      } else {
        float e = expf(li - m[d]);
        s[d] += e;
        if (d == 3) sl += e * li;
      }
    }
  }
#pragma unroll
  for (int off = 32; off; off >>= 1) {
#pragma unroll
    for (int d = 0; d < 3; ++d) {
      float om = __shfl_down(m[d], off);
      float os = __shfl_down(s[d], off);
      comb(m[d], s[d], om, os);
    }
    float om = __shfl_down(m[3], off);
    float os = __shfl_down(s[3], off);
    float osl = __shfl_down(sl, off);
    comb_sl(m[3], s[3], sl, om, os, osl);
  }
  int wv = tid >> 6, ln = tid & 63;
  if (ln == 0) {
#pragma unroll
    for (int d = 0; d < 4; ++d) { rm[wv][d] = m[d]; rs[wv][d] = s[d]; }
    rsl2[wv] = sl;
  }
  __syncthreads();
  if (tid == 0) {
    float* part = ws + WS_PART + ((size_t)t * NCH + ch) * 9;
    for (int d = 0; d < 3; ++d) {
      float M = rm[0][d], S = rs[0][d];
      for (int w2 = 1; w2 < 4; ++w2) comb(M, S, rm[w2][d], rs[w2][d]);
      part[d] = M; part[4 + d] = S;
    }
    float M = rm[0][3], S = rs[0][3], SL = rsl2[0];
    for (int w2 = 1; w2 < 4; ++w2) comb_sl(M, S, SL, rm[w2][3], rs[w2][3], rsl2[w2]);
    part[3] = M; part[7] = S; part[8] = SL;
  }
}

// ---------- k_final: [0,64) eig(+S,H,F) | [64,..) norm writes ----------
// eig blocks FIRST (latency chain starts at t=0 of dispatch); the ~51.5MB
// slow out-writes of the norm blocks overlap the eig chain on the other CUs.
// norm does NOT depend on eig (lz from WS_PART only); H/F written by eig.
__global__ void k_final(float* __restrict__ ws, float* __restrict__ out) {
  __shared__ float A[Jc * 25];         // eig; stride 25: bank-decorrelated
  __shared__ float wsh[Jc];
  __shared__ float lzs[4];
  int bid = blockIdx.x, tid = threadIdx.x;

  if (bid < Tc) {
    if (tid >= 64) return;
    int t = bid, lane = tid;
    for (int i = lane; i < Jc * Jc; i += 64) {
      int r = i / Jc, c = i % Jc;
      A[r * 25 + c] = ws[WS_G + i] *
                      sqrtf(ws[WS_WALL + (size_t)t * Jc + r] * ws[WS_WALL + (size_t)t * Jc + c]) *
                      (1.f / 3.f);
    }
    __builtin_amdgcn_wave_barrier();
    for (int sweep = 0; sweep < 7; ++sweep) {
      for (int rr = 0; rr < 23; ++rr) {
        float cv = 1.f, sv = 0.f;
        if (lane < Jc) {
          int j = lane;
          int m = (j == 23) ? rr : ((j == rr) ? 23 : (2 * rr + 23 - j) % 23);
          int lo = min(j, m), hi = max(j, m);
          float ajj = A[j * 25 + j];
          float alh = A[lo * 25 + hi];
          float amm = __shfl(ajj, m);
          float app = (j == lo) ? ajj : amm;
          float aqq = (j == lo) ? amm : ajj;
          if (fabsf(alh) > 1e-20f) {
            float th = (aqq - app) / (2.f * alh);
            float tt = 1.f / (fabsf(th) + sqrtf(1.f + th * th));
            if (th < 0.f) tt = -tt;
            cv = 1.f / sqrtf(1.f + tt * tt);
            sv = tt * cv;
          }
        }
        __builtin_amdgcn_wave_barrier();
#pragma unroll
        for (int it = 0; it < 3; ++it) {
          int b = lane + 64 * it;
          int bb = (b < 144) ? b : 143;
          int pi = bb / 12, pj = bb % 12;
          int p0, q0, p1, q1;
          if (pi == 0) { p0 = rr; q0 = 23; }
          else { int a = (rr + pi) % 23, b2 = (rr + 23 - pi) % 23; p0 = min(a, b2); q0 = max(a, b2); }
          if (pj == 0) { p1 = rr; q1 = 23; }
          else { int a = (rr + pj) % 23, b2 = (rr + 23 - pj) % 23; p1 = min(a, b2); q1 = max(a, b2); }
          float ci = __shfl(cv, p0), si = __shfl(sv, p0);
          float cj = __shfl(cv, p1), sj = __shfl(sv, p1);
          if (b < 144) {
            float m00 = A[p0 * 25 + p1], m01 = A[p0 * 25 + q1];
            float m10 = A[q0 * 25 + p1], m11 = A[q0 * 25 + q1];
            float r00 = ci * m00 - si * m10, r01 = ci * m01 - si * m11;
            float r10 = si * m00 + ci * m10, r11 = si * m01 + ci * m11;
            float o00 = cj * r00 - sj * r01, o01 = sj * r00 + cj * r01;
            float o10 = cj * r10 - sj * r11, o11 = sj * r10 + cj * r11;
            A[p0 * 25 + p1] = o00; A[p0 * 25 + q1] = o01;
            A[q0 * 25 + p1] = o10; A[q0 * 25 + q1] = o11;
          }
        }
        __builtin_amdgcn_wave_barrier();
      }
    }
    float lam = 0.f;
    if (lane < Jc) lam = fmaxf(A[lane * 25 + lane], 1e-12f);
    float tot = lam;
#pragma unroll
    for (int off = 32; off; off >>= 1) tot += __shfl_down(tot, off);
    tot = __shfl(tot, 0);
    tot += (float)(Dc - Jc) * 1e-12f;
    float term = 0.f;
    if (lane < Jc) { float p = lam / tot; term = p * logf(p); }
#pragma unroll
    for (int off = 32; off; off >>= 1) term += __shfl_down(term, off);
    if (lane == 0) {
      float pe = 1e-12f / tot;
      float Srho = -(term + (float)(Dc - Jc) * pe * logf(pe));
      out[OFF_S + t] = Srho;
      // d=3 logZ reduce, identical ch-order to old k_reduce
      float M = -INFINITY, S = 0.f, SL = 0.f;
      for (int ch = 0; ch < NCH; ++ch) {
        const float* pp = ws + WS_PART + ((size_t)t * NCH + ch) * 9;
        comb_sl(M, S, SL, pp[3], pp[7], pp[8]);
      }
      float lz = M + logf(S);
      float H = lz - SL / S;
      out[OFF_H + t] = H;
      out[OFF_F + t] = H - Srho;
    }
    return;
  }

  // ----- norm branch: recompute logits, write all 4 prob streams -----
  int lin = bid - Tc;
  int t = lin / NCH, ch = lin % NCH;
  if (tid < Jc) wsh[tid] = ws[WS_WALL + (size_t)t * Jc + tid];
  if (tid >= 32 && tid < 36) {
    int d = tid - 32;
    float M = -INFINITY, S = 0.f, SL = 0.f;
    for (int c2 = 0; c2 < NCH; ++c2) {
      const float* pp = ws + WS_PART + ((size_t)t * NCH + c2) * 9;
      if (d == 3) comb_sl(M, S, SL, pp[3], pp[7], pp[8]);
      else        comb(M, S, pp[d], pp[4 + d]);
    }
    lzs[d] = M + logf(S);
  }
  __syncthreads();
  float lz0 = lzs[0], lz1 = lzs[1], lz2 = lzs[2], lz3 = lzs[3];
  const float* p2 = ws + WS_P2T;
  for (int r = 0; r < 4; ++r) {
    int v = ch * CHV + r * 256 + tid;
    if (v >= Vv) break;
    float l0, l1, l2;
    logits_from_row(p2, wsh, v, l0, l1, l2);
    float l3 = (l0 + l1 + l2) * (1.f / 3.f);
    out[OFF_TOK + (size_t)t * Vv + v] = expf(l3 - lz3);
    out[OFF_PF + ((size_t)t * Kc + 0) * Vv + v] = expf(l0 - lz0);
    out[OFF_PF + ((size_t)t * Kc + 1) * Vv + v] = expf(l1 - lz1);
    out[OFF_PF + ((size_t)t * Kc + 2) * Vv + v] = expf(l2 - lz2);
  }
}

extern "C" void kernel_launch(void* const* d_in, const int* in_sizes, int n_in,
                              void* d_out, int out_size, void* d_ws, size_t ws_size,
                              hipStream_t stream) {
  const int*   tokens = (const int*)d_in[0];
  const float* E      = (const float*)d_in[1];
  const float* bub    = (const float*)d_in[2];
  const float* pdb    = (const float*)d_in[3];
  const float* psn    = (const float*)d_in[4];
  float* out = (float*)d_out;
  float* ws  = (float*)d_ws;

  k_setup<<<1 + Tc + (Vv + 255) / 256, 256, 0, stream>>>(tokens, E, bub, ws);
  k_recur<<<1, 64, 0, stream>>>(tokens, E, bub, pdb, psn, ws);
  k_part<<<Tc + Tc * NCH, 256, 0, stream>>>(ws, out);
  k_final<<<Tc + Tc * NCH, 256, 0, stream>>>(ws, out);
}